// Round 6
// baseline (641.449 us; speedup 1.0000x reference)
//
#include <hip/hip_runtime.h>
#include <hip/hip_bf16.h>
#include <cstdint>

// ---------------------------------------------------------------------------
// GraphSAGE inference. bf16 GEMM plane (MFMA, async LDS staging); fp8 e4m3
// aggregation tables; XCD-sliced CSR build (write-amplification fix, round 6).
//   CSR build (sliced count -> 3-phase scan -> sliced scatter)
//   agg256_fp8(x8) -> A1b
//   gemm([xb|A1b]@Wt0)+b0 relu -> H0b(bf16) + H08(fp8)
//   agg256_fp8(H08) -> A1b
//   gemm([H0b|A1b]@Wt1)+b1 relu -> h1(fp32) + h1b(bf16)
//   gemm(h1b@[Ws2t;Wn2t]) -> Sself(fp32), Tb(bf16)
//   agg64_final: h2 = Sself + mean_csr(Tb) + b2
// ---------------------------------------------------------------------------

typedef __attribute__((ext_vector_type(8))) short  frag_ab;  // 8 bf16
typedef __attribute__((ext_vector_type(4))) float  f32x4;
typedef __attribute__((ext_vector_type(2))) float  vf2;

#define NSLICE 8
#define NCHUNK 512

__device__ __forceinline__ unsigned short f2b(float f) {
    __hip_bfloat16 h = __float2bfloat16(f);
    return *reinterpret_cast<unsigned short*>(&h);
}
__device__ __forceinline__ unsigned char f2p8(float f) {
    int p = __builtin_amdgcn_cvt_pk_fp8_f32(f, f, 0, false);
    return (unsigned char)(p & 0xff);
}
// accumulate 8 bf16 (as uint4) into 8 fp32
__device__ __forceinline__ void acc8(float* a, uint4 v) {
    a[0] += __uint_as_float(v.x << 16);
    a[1] += __uint_as_float(v.x & 0xffff0000u);
    a[2] += __uint_as_float(v.y << 16);
    a[3] += __uint_as_float(v.y & 0xffff0000u);
    a[4] += __uint_as_float(v.z << 16);
    a[5] += __uint_as_float(v.z & 0xffff0000u);
    a[6] += __uint_as_float(v.w << 16);
    a[7] += __uint_as_float(v.w & 0xffff0000u);
}
// accumulate 16 fp8 (as uint4) into 16 fp32 via HW cvt
__device__ __forceinline__ void acc16p(float* a, uint4 v) {
    vf2 f0 = __builtin_amdgcn_cvt_pk_f32_fp8(v.x, false);
    vf2 f1 = __builtin_amdgcn_cvt_pk_f32_fp8(v.x, true);
    vf2 f2 = __builtin_amdgcn_cvt_pk_f32_fp8(v.y, false);
    vf2 f3 = __builtin_amdgcn_cvt_pk_f32_fp8(v.y, true);
    a[0] += f0.x; a[1] += f0.y; a[2] += f1.x; a[3] += f1.y;
    a[4] += f2.x; a[5] += f2.y; a[6] += f3.x; a[7] += f3.y;
    vf2 f4 = __builtin_amdgcn_cvt_pk_f32_fp8(v.z, false);
    vf2 f5 = __builtin_amdgcn_cvt_pk_f32_fp8(v.z, true);
    vf2 f6 = __builtin_amdgcn_cvt_pk_f32_fp8(v.w, false);
    vf2 f7 = __builtin_amdgcn_cvt_pk_f32_fp8(v.w, true);
    a[8]  += f4.x; a[9]  += f4.y; a[10] += f5.x; a[11] += f5.y;
    a[12] += f6.x; a[13] += f6.y; a[14] += f7.x; a[15] += f7.y;
}

// async global->LDS, 16B per lane; lds base wave-uniform (HW adds lane*16)
__device__ __forceinline__ void gl_lds16(const void* g, void* l) {
    __builtin_amdgcn_global_load_lds(
        (const __attribute__((address_space(1))) unsigned int*)g,
        (__attribute__((address_space(3))) unsigned int*)l, 16, 0, 0);
}

// ---------------- CSR build (XCD-sliced) ----------------
// slice = blockIdx.x & 7 (heuristic XCD id); each slice-group scans all edges,
// touches only its dst range -> deg/csr writes stay in one XCD's L2.
__global__ __launch_bounds__(256) void count_deg_sliced(
    const int* __restrict__ dst, int* __restrict__ deg, int E, int sliceW) {
    const int slice = blockIdx.x & (NSLICE - 1);
    const int chunk = blockIdx.x >> 3;
    const int lo = slice * sliceW, hi = lo + sliceW;
    const int per = (E + NCHUNK - 1) / NCHUNK;
    const int e0 = chunk * per;
    const int e1 = min(e0 + per, E);
    for (int e = e0 + threadIdx.x; e < e1; e += 256) {
        int d = dst[e];
        if (d >= lo && d < hi) atomicAdd(&deg[d], 1);
    }
}

__global__ __launch_bounds__(256) void scatter_edges_sliced(
    const int* __restrict__ src, const int* __restrict__ dst,
    const int* __restrict__ row_start, int* __restrict__ cursor,
    int* __restrict__ csr, int E, int sliceW) {
    const int slice = blockIdx.x & (NSLICE - 1);
    const int chunk = blockIdx.x >> 3;
    const int lo = slice * sliceW, hi = lo + sliceW;
    const int per = (E + NCHUNK - 1) / NCHUNK;
    const int e0 = chunk * per;
    const int e1 = min(e0 + per, E);
    for (int e = e0 + threadIdx.x; e < e1; e += 256) {
        int d = dst[e];
        if (d >= lo && d < hi) {
            int pos = atomicAdd(&cursor[d], 1);
            csr[row_start[d] + pos] = src[e];
        }
    }
}

__global__ __launch_bounds__(256) void scan_partial_kernel(
    const int* __restrict__ deg, int* __restrict__ partials, int n) {
    const int t = threadIdx.x;
    const int i0 = blockIdx.x * 1024 + t * 4;
    int sum = 0;
#pragma unroll
    for (int j = 0; j < 4; j++) { int i = i0 + j; if (i < n) sum += deg[i]; }
#pragma unroll
    for (int off = 32; off; off >>= 1) sum += __shfl_down(sum, off);
    __shared__ int ws[4];
    int lane = t & 63, wid = t >> 6;
    if (lane == 0) ws[wid] = sum;
    __syncthreads();
    if (t == 0) partials[blockIdx.x] = ws[0] + ws[1] + ws[2] + ws[3];
}

__global__ void scan_partials_kernel(int* __restrict__ p, int nb) {
    const int lane = threadIdx.x;  // 64 threads
    int carry = 0;
    for (int base = 0; base < nb; base += 64) {
        int i = base + lane;
        int v = (i < nb) ? p[i] : 0;
        int orig = v;
#pragma unroll
        for (int off = 1; off < 64; off <<= 1) {
            int x = __shfl_up(v, off);
            if (lane >= off) v += x;
        }
        int ex = carry + v - orig;
        if (i < nb) p[i] = ex;
        carry += __shfl(v, 63);
    }
}

__global__ __launch_bounds__(256) void scan_final_kernel(
    const int* __restrict__ deg, const int* __restrict__ pscan,
    int* __restrict__ row_start, int n) {
    const int t = threadIdx.x;
    const int i0 = blockIdx.x * 1024 + t * 4;
    int v0 = (i0 + 0 < n) ? deg[i0 + 0] : 0;
    int v1 = (i0 + 1 < n) ? deg[i0 + 1] : 0;
    int v2 = (i0 + 2 < n) ? deg[i0 + 2] : 0;
    int v3 = (i0 + 3 < n) ? deg[i0 + 3] : 0;
    int tot = v0 + v1 + v2 + v3;
    int lane = t & 63, wid = t >> 6;
    int inc = tot;
#pragma unroll
    for (int off = 1; off < 64; off <<= 1) {
        int x = __shfl_up(inc, off);
        if (lane >= off) inc += x;
    }
    __shared__ int wsum[4];
    if (lane == 63) wsum[wid] = inc;
    __syncthreads();
    int wbase = 0;
    for (int w2 = 0; w2 < wid; w2++) wbase += wsum[w2];
    int r = wbase + inc - tot + pscan[blockIdx.x];
    r += v0; if (i0 + 0 < n) row_start[i0 + 1] = r;
    r += v1; if (i0 + 1 < n) row_start[i0 + 2] = r;
    r += v2; if (i0 + 2 < n) row_start[i0 + 3] = r;
    r += v3; if (i0 + 3 < n) row_start[i0 + 4] = r;
    if (blockIdx.x == 0 && t == 0) row_start[0] = 0;
}

// ---------------- conversions ----------------
__global__ void conv_x_kernel(const float* __restrict__ in, unsigned short* __restrict__ outb,
                              unsigned char* __restrict__ outp, int n4) {
    int i = blockIdx.x * blockDim.x + threadIdx.x;
    if (i >= n4) return;
    float4 v = *reinterpret_cast<const float4*>(in + (size_t)i * 4);
    ushort4 ob = { f2b(v.x), f2b(v.y), f2b(v.z), f2b(v.w) };
    *reinterpret_cast<ushort4*>(outb + (size_t)i * 4) = ob;
    int p0 = __builtin_amdgcn_cvt_pk_fp8_f32(v.x, v.y, 0, false);
    int p1 = __builtin_amdgcn_cvt_pk_fp8_f32(v.z, v.w, 0, false);
    unsigned int packed = (unsigned int)(p0 & 0xffff) | ((unsigned int)p1 << 16);
    *reinterpret_cast<unsigned int*>(outp + (size_t)i * 4) = packed;
}

// all six weight transposes in one dispatch.
__global__ __launch_bounds__(256) void wt_all_kernel(
    const float* __restrict__ Ws0, const float* __restrict__ Wn0,
    const float* __restrict__ Ws1, const float* __restrict__ Wn1,
    const float* __restrict__ Ws2, const float* __restrict__ Wn2,
    unsigned short* __restrict__ Wt0, unsigned short* __restrict__ Wt1,
    unsigned short* __restrict__ Wt2) {
    int b = blockIdx.x;
    const float* W; unsigned short* Wt; int N, koff, Ktot, noff, idx;
    if (b < 1024) {
        int seg = b >> 8; idx = (b & 255) * 256 + threadIdx.x;
        N = 256; Ktot = 512; noff = 0;
        if (seg == 0)      { W = Ws0; Wt = Wt0; koff = 0;   }
        else if (seg == 1) { W = Wn0; Wt = Wt0; koff = 256; }
        else if (seg == 2) { W = Ws1; Wt = Wt1; koff = 0;   }
        else               { W = Wn1; Wt = Wt1; koff = 256; }
    } else {
        int seg = (b - 1024) >> 6; idx = ((b - 1024) & 63) * 256 + threadIdx.x;
        N = 64; Ktot = 256; koff = 0;
        if (seg == 0) { W = Ws2; Wt = Wt2; noff = 0;  }
        else          { W = Wn2; Wt = Wt2; noff = 64; }
    }
    int k = idx / N, n = idx - k * N;
    Wt[(size_t)(n + noff) * Ktot + koff + k] = f2b(W[(size_t)idx]);
}

// ---------------- aggregation ----------------
// fp8 rows (256B). Quarter-wave q covers one edge's row (16 lanes x 16B dwordx4).
// 4 edges per quarter in flight (16/wave). bf16 output row.
__global__ __launch_bounds__(256) void agg256_fp8(
    const unsigned char* __restrict__ hsrc, const int* __restrict__ row_start,
    const int* __restrict__ csr, unsigned short* __restrict__ out, int n) {
    int wv = (blockIdx.x * blockDim.x + threadIdx.x) >> 6;
    int lane = threadIdx.x & 63;
    if (wv >= n) return;
    int s0 = row_start[wv], s1 = row_start[wv + 1];
    int deg = s1 - s0;
    const int q  = lane >> 4;     // 0..3: edge sub-stream
    const int li = lane & 15;     // 16B chunk -> fp8 cols li*16..li*16+15
    float a[16];
#pragma unroll
    for (int k = 0; k < 16; k++) a[k] = 0.f;

    for (int base = s0; base < s1; base += 16) {
        int idx[4];
#pragma unroll
        for (int j = 0; j < 4; j++) {
            int e = base + q + 4 * j;
            idx[j] = csr[e < s1 ? e : s1 - 1];
        }
        uint4 v[4];
#pragma unroll
        for (int j = 0; j < 4; j++) {
            int e = base + q + 4 * j;
            v[j] = make_uint4(0u, 0u, 0u, 0u);
            if (e < s1)
                v[j] = *reinterpret_cast<const uint4*>(hsrc + (size_t)idx[j] * 256 + li * 16);
        }
#pragma unroll
        for (int j = 0; j < 4; j++) acc16p(a, v[j]);
    }
#pragma unroll
    for (int k = 0; k < 16; k++) {
        a[k] += __shfl_xor(a[k], 16);
        a[k] += __shfl_xor(a[k], 32);
    }
    if (q == 0) {
        float sc = 1.0f / (float)max(deg, 1);
        uint4 o0, o1;
        o0.x = ((unsigned)f2b(a[1]  * sc) << 16) | f2b(a[0]  * sc);
        o0.y = ((unsigned)f2b(a[3]  * sc) << 16) | f2b(a[2]  * sc);
        o0.z = ((unsigned)f2b(a[5]  * sc) << 16) | f2b(a[4]  * sc);
        o0.w = ((unsigned)f2b(a[7]  * sc) << 16) | f2b(a[6]  * sc);
        o1.x = ((unsigned)f2b(a[9]  * sc) << 16) | f2b(a[8]  * sc);
        o1.y = ((unsigned)f2b(a[11] * sc) << 16) | f2b(a[10] * sc);
        o1.z = ((unsigned)f2b(a[13] * sc) << 16) | f2b(a[12] * sc);
        o1.w = ((unsigned)f2b(a[15] * sc) << 16) | f2b(a[14] * sc);
        *reinterpret_cast<uint4*>(out + (size_t)wv * 256 + li * 16) = o0;
        *reinterpret_cast<uint4*>(out + (size_t)wv * 256 + li * 16 + 8) = o1;
    }
}

// h2[v][:] = Sself[v][:] + mean_{s in N(v)} Tb[s][:] + b2 ; Tb bf16 64-wide
__global__ __launch_bounds__(256) void agg64_final(
    const unsigned short* __restrict__ t, const int* __restrict__ row_start,
    const int* __restrict__ csr, const float* __restrict__ Sself,
    const float* __restrict__ b2, float* __restrict__ h2, int n) {
    int wv = (blockIdx.x * blockDim.x + threadIdx.x) >> 6;
    int lane = threadIdx.x & 63;
    if (wv >= n) return;
    int s0 = row_start[wv], s1 = row_start[wv + 1];
    int deg = s1 - s0;
    const int g  = lane >> 3;
    const int li = lane & 7;
    float a[8] = {0.f, 0.f, 0.f, 0.f, 0.f, 0.f, 0.f, 0.f};
    for (int base = s0 + g; base < s1; base += 16) {
        int e1 = base + 8;
        int i0 = csr[base];
        int i1 = csr[e1 < s1 ? e1 : s1 - 1];
        uint4 v0 = *reinterpret_cast<const uint4*>(t + (size_t)i0 * 64 + li * 8);
        uint4 v1 = make_uint4(0u, 0u, 0u, 0u);
        if (e1 < s1)
            v1 = *reinterpret_cast<const uint4*>(t + (size_t)i1 * 64 + li * 8);
        acc8(a, v0); acc8(a, v1);
    }
#pragma unroll
    for (int k = 0; k < 8; k++) {
        a[k] += __shfl_xor(a[k], 8);
        a[k] += __shfl_xor(a[k], 16);
        a[k] += __shfl_xor(a[k], 32);
    }
    if (g == 0) {
        float sc = 1.0f / (float)max(deg, 1);
        float4 s0v = *reinterpret_cast<const float4*>(Sself + (size_t)wv * 64 + li * 8);
        float4 s1v = *reinterpret_cast<const float4*>(Sself + (size_t)wv * 64 + li * 8 + 4);
        float4 bb0 = *reinterpret_cast<const float4*>(b2 + li * 8);
        float4 bb1 = *reinterpret_cast<const float4*>(b2 + li * 8 + 4);
        float4 o0 = make_float4(s0v.x + a[0] * sc + bb0.x, s0v.y + a[1] * sc + bb0.y,
                                s0v.z + a[2] * sc + bb0.z, s0v.w + a[3] * sc + bb0.w);
        float4 o1 = make_float4(s1v.x + a[4] * sc + bb1.x, s1v.y + a[5] * sc + bb1.y,
                                s1v.z + a[6] * sc + bb1.z, s1v.w + a[7] * sc + bb1.w);
        *reinterpret_cast<float4*>(h2 + (size_t)wv * 64 + li * 8) = o0;
        *reinterpret_cast<float4*>(h2 + (size_t)wv * 64 + li * 8 + 4) = o1;
    }
}

// ---------------- MFMA GEMM with async LDS staging ----------------
#define TM 128
#define TN 64
#define TK 32

__global__ __launch_bounds__(256) void gemm_mfma(
    const unsigned short* __restrict__ A, const unsigned short* __restrict__ G,
    const unsigned short* __restrict__ Wt, const float* __restrict__ bias,
    float* __restrict__ outF, unsigned short* __restrict__ outB,
    unsigned char* __restrict__ outP,
    int M, int Ntot, int Ktot, int relu, int split) {
    __shared__ unsigned short Asb[TM][TK];   // unpadded: lane-linear for lds-dma
    __shared__ unsigned short Bsb[TN][TK];

    const int tid = threadIdx.x;
    const int row0 = blockIdx.x * TM;
    const int col0 = blockIdx.y * TN;

    const int w = tid >> 6, lane = tid & 63;
    const int mw = (w & 1) * 64;
    const int nw = (w >> 1) * 32;
    const int lm = lane & 15, lq = lane >> 4;
    const int lr = lane >> 2;
    const int lc = (lane & 3) * 8;

    f32x4 acc[4][2];
#pragma unroll
    for (int i = 0; i < 4; i++)
#pragma unroll
        for (int j = 0; j < 2; j++) acc[i][j] = (f32x4)(0.f);

    for (int k0 = 0; k0 < Ktot; k0 += TK) {
        const unsigned short* __restrict__ Ap = (G != nullptr && k0 >= 256) ? G : A;
        const int kl = k0 & 255;
#pragma unroll
        for (int h = 0; h < 2; ++h) {
            int r16 = w * 32 + h * 16;
            int gr = row0 + r16 + lr;
            if (gr < M)
                gl_lds16(Ap + (size_t)gr * 256 + kl + lc, &Asb[r16][0]);
        }
        {
            int n16 = w * 16;
            int gn = col0 + n16 + lr;
            gl_lds16(Wt + (size_t)gn * Ktot + k0 + lc, &Bsb[n16][0]);
        }
        __syncthreads();

        frag_ab a[4], b[2];
#pragma unroll
        for (int i = 0; i < 4; i++)
            a[i] = *reinterpret_cast<const frag_ab*>(&Asb[mw + i * 16 + lm][lq * 8]);
#pragma unroll
        for (int j = 0; j < 2; j++)
            b[j] = *reinterpret_cast<const frag_ab*>(&Bsb[nw + j * 16 + lm][lq * 8]);
#pragma unroll
        for (int i = 0; i < 4; i++)
#pragma unroll
            for (int j = 0; j < 2; j++)
                acc[i][j] = __builtin_amdgcn_mfma_f32_16x16x32_bf16(a[i], b[j], acc[i][j], 0, 0, 0);
        __syncthreads();
    }

#pragma unroll
    for (int i = 0; i < 4; i++) {
#pragma unroll
        for (int j = 0; j < 2; j++) {
            int cg = col0 + nw + j * 16 + lm;
#pragma unroll
            for (int r = 0; r < 4; r++) {
                int rg = row0 + mw + i * 16 + lq * 4 + r;
                if (rg >= M) continue;
                float v = acc[i][j][r];
                if (bias) v += bias[cg];
                if (relu) v = fmaxf(v, 0.f);
                if (split) {
                    if (cg < 64) outF[(size_t)rg * 64 + cg] = v;
                    else         outB[(size_t)rg * 64 + (cg - 64)] = f2b(v);
                } else {
                    if (outF) outF[(size_t)rg * Ntot + cg] = v;
                    if (outB) outB[(size_t)rg * Ntot + cg] = f2b(v);
                    if (outP) outP[(size_t)rg * Ntot + cg] = f2p8(v);
                }
            }
        }
    }
}

// ---------------------------------------------------------------------------
extern "C" void kernel_launch(void* const* d_in, const int* in_sizes, int n_in,
                              void* d_out, int out_size, void* d_ws, size_t ws_size,
                              hipStream_t stream) {
    const float* x   = (const float*)d_in[0];
    const int*   src = (const int*)d_in[1];
    const int*   dst = (const int*)d_in[2];
    const float* Ws0 = (const float*)d_in[3];
    const float* Wn0 = (const float*)d_in[4];
    const float* b0  = (const float*)d_in[5];
    const float* Ws1 = (const float*)d_in[6];
    const float* Wn1 = (const float*)d_in[7];
    const float* b1  = (const float*)d_in[8];
    const float* Ws2 = (const float*)d_in[9];
    const float* Wn2 = (const float*)d_in[10];
    const float* b2  = (const float*)d_in[11];

    const int N = in_sizes[0] / 256;   // 50000
    const int E = in_sizes[1];         // 1600000

    float* out = (float*)d_out;
    float* h2 = out;                       // N x 64  (output 0)
    float* h1 = out + (size_t)N * 64;      // N x 256 (output 1, fp32)

    // ---- workspace layout ----
    char* w = (char*)d_ws;
    auto align16 = [](char* p) { return (char*)(((uintptr_t)p + 15) & ~(uintptr_t)15); };
    int* deg       = (int*)w;  w += (size_t)N * 4;
    int* cursor    = (int*)w;  w += (size_t)N * 4;
    int* row_start = (int*)w;  w += (size_t)(N + 1) * 4;
    int* partials  = (int*)w;  w += 256 * 4;
    int* csr       = (int*)w;  w += (size_t)E * 4;
    w = align16(w);
    unsigned short* Wt0   = (unsigned short*)w; w += (size_t)256 * 512 * 2;
    unsigned short* Wt1   = (unsigned short*)w; w += (size_t)256 * 512 * 2;
    unsigned short* Wt2   = (unsigned short*)w; w += (size_t)128 * 256 * 2;  // [Ws2t;Wn2t]
    w = align16(w);
    unsigned short* xb    = (unsigned short*)w; w += (size_t)N * 256 * 2;
    unsigned short* A1b   = (unsigned short*)w; w += (size_t)N * 256 * 2;
    unsigned short* H0b   = (unsigned short*)w; w += (size_t)N * 256 * 2;
    unsigned short* h1b   = (unsigned short*)w; w += (size_t)N * 256 * 2;
    // dead-region aliases (zero extra workspace):
    unsigned char* x8  = (unsigned char*)H0b;  // dead once gemm0 writes H0b
    unsigned char* H08 = (unsigned char*)h1b;  // consumed by agg#2 before gemm1 writes h1b
    unsigned short* Tb    = xb;                // xb dead after gemm0
    float*          Sself = (float*)A1b;       // A1b dead after gemm1

    const int nb = (N + 1023) / 1024;
    const int sliceW = (N + NSLICE - 1) / NSLICE;

    // ---- CSR build (XCD-sliced) ----
    hipMemsetAsync(deg, 0, (size_t)N * 2 * 4, stream);
    count_deg_sliced<<<NSLICE * NCHUNK, 256, 0, stream>>>(dst, deg, E, sliceW);
    scan_partial_kernel<<<nb, 256, 0, stream>>>(deg, partials, N);
    scan_partials_kernel<<<1, 64, 0, stream>>>(partials, nb);
    scan_final_kernel<<<nb, 256, 0, stream>>>(deg, partials, row_start, N);
    scatter_edges_sliced<<<NSLICE * NCHUNK, 256, 0, stream>>>(src, dst, row_start, cursor,
                                                              csr, E, sliceW);

    // ---- conversions ----
    {
        int n4 = N * 256 / 4;
        conv_x_kernel<<<(n4 + 255) / 256, 256, 0, stream>>>(x, xb, x8, n4);
    }
    wt_all_kernel<<<1152, 256, 0, stream>>>(Ws0, Wn0, Ws1, Wn1, Ws2, Wn2, Wt0, Wt1, Wt2);

    dim3 aggGrid((N + 3) / 4);
    dim3 gBig((N + TM - 1) / TM, 256 / TN);    // 391 x 4
    dim3 gSplit((N + TM - 1) / TM, 2);         // 391 x 2

    // ---- layer 0 ----
    agg256_fp8<<<aggGrid, 256, 0, stream>>>(x8, row_start, csr, A1b, N);
    gemm_mfma<<<gBig, 256, 0, stream>>>(xb, A1b, Wt0, b0, nullptr, H0b, H08,
                                        N, 256, 512, 1, 0);
    // ---- layer 1 ----
    agg256_fp8<<<aggGrid, 256, 0, stream>>>(H08, row_start, csr, A1b, N);
    gemm_mfma<<<gBig, 256, 0, stream>>>(H0b, A1b, Wt1, b1, h1, h1b, nullptr,
                                        N, 256, 512, 1, 0);
    // ---- layer 2: stacked gemm + fused aggregate/add ----
    gemm_mfma<<<gSplit, 256, 0, stream>>>(h1b, nullptr, Wt2, nullptr, Sself, Tb, nullptr,
                                          N, 128, 256, 0, 1);
    agg64_final<<<aggGrid, 256, 0, stream>>>(Tb, row_start, csr, Sself, b2, h2, N);
}

// Round 7
// 580.059 us; speedup vs baseline: 1.1058x; 1.1058x over previous
//
#include <hip/hip_runtime.h>
#include <hip/hip_bf16.h>
#include <cstdint>

// ---------------------------------------------------------------------------
// GraphSAGE inference. bf16 GEMM plane (MFMA, async LDS staging); fp8 e4m3
// aggregation tables; XCD-sliced CSR build.
// Round 7: big GEMMs restructured to TM=128 x TN=256 single-block row-stripes
// (512 thr, 8 waves) so the A|G operand is fetched from HBM exactly once.
//   CSR build -> agg256_fp8(x8) -> A1b
//   gemm_big512([xb|A1b]@Wt0)+b0 relu -> H0b(bf16) + H08(fp8)
//   agg256_fp8(H08) -> A1b
//   gemm_big512([H0b|A1b]@Wt1)+b1 relu -> h1(fp32) + h1b(bf16)
//   gemm_mfma(h1b@[Ws2t;Wn2t]) -> Sself(fp32), Tb(bf16)
//   agg64_final: h2 = Sself + mean_csr(Tb) + b2
// ---------------------------------------------------------------------------

typedef __attribute__((ext_vector_type(8))) short  frag_ab;  // 8 bf16
typedef __attribute__((ext_vector_type(4))) float  f32x4;
typedef __attribute__((ext_vector_type(2))) float  vf2;

#define NSLICE 8
#define NCHUNK 512

__device__ __forceinline__ unsigned short f2b(float f) {
    __hip_bfloat16 h = __float2bfloat16(f);
    return *reinterpret_cast<unsigned short*>(&h);
}
__device__ __forceinline__ unsigned char f2p8(float f) {
    int p = __builtin_amdgcn_cvt_pk_fp8_f32(f, f, 0, false);
    return (unsigned char)(p & 0xff);
}
// accumulate 8 bf16 (as uint4) into 8 fp32
__device__ __forceinline__ void acc8(float* a, uint4 v) {
    a[0] += __uint_as_float(v.x << 16);
    a[1] += __uint_as_float(v.x & 0xffff0000u);
    a[2] += __uint_as_float(v.y << 16);
    a[3] += __uint_as_float(v.y & 0xffff0000u);
    a[4] += __uint_as_float(v.z << 16);
    a[5] += __uint_as_float(v.z & 0xffff0000u);
    a[6] += __uint_as_float(v.w << 16);
    a[7] += __uint_as_float(v.w & 0xffff0000u);
}
// accumulate 16 fp8 (as uint4) into 16 fp32 via HW cvt
__device__ __forceinline__ void acc16p(float* a, uint4 v) {
    vf2 f0 = __builtin_amdgcn_cvt_pk_f32_fp8(v.x, false);
    vf2 f1 = __builtin_amdgcn_cvt_pk_f32_fp8(v.x, true);
    vf2 f2 = __builtin_amdgcn_cvt_pk_f32_fp8(v.y, false);
    vf2 f3 = __builtin_amdgcn_cvt_pk_f32_fp8(v.y, true);
    a[0] += f0.x; a[1] += f0.y; a[2] += f1.x; a[3] += f1.y;
    a[4] += f2.x; a[5] += f2.y; a[6] += f3.x; a[7] += f3.y;
    vf2 f4 = __builtin_amdgcn_cvt_pk_f32_fp8(v.z, false);
    vf2 f5 = __builtin_amdgcn_cvt_pk_f32_fp8(v.z, true);
    vf2 f6 = __builtin_amdgcn_cvt_pk_f32_fp8(v.w, false);
    vf2 f7 = __builtin_amdgcn_cvt_pk_f32_fp8(v.w, true);
    a[8]  += f4.x; a[9]  += f4.y; a[10] += f5.x; a[11] += f5.y;
    a[12] += f6.x; a[13] += f6.y; a[14] += f7.x; a[15] += f7.y;
}

// async global->LDS, 16B per lane; lds base wave-uniform (HW adds lane*16)
__device__ __forceinline__ void gl_lds16(const void* g, void* l) {
    __builtin_amdgcn_global_load_lds(
        (const __attribute__((address_space(1))) unsigned int*)g,
        (__attribute__((address_space(3))) unsigned int*)l, 16, 0, 0);
}

// ---------------- CSR build (XCD-sliced) ----------------
__global__ __launch_bounds__(256) void count_deg_sliced(
    const int* __restrict__ dst, int* __restrict__ deg, int E, int sliceW) {
    const int slice = blockIdx.x & (NSLICE - 1);
    const int chunk = blockIdx.x >> 3;
    const int lo = slice * sliceW, hi = lo + sliceW;
    const int per = (E + NCHUNK - 1) / NCHUNK;
    const int e0 = chunk * per;
    const int e1 = min(e0 + per, E);
    for (int e = e0 + threadIdx.x; e < e1; e += 256) {
        int d = dst[e];
        if (d >= lo && d < hi) atomicAdd(&deg[d], 1);
    }
}

__global__ __launch_bounds__(256) void scatter_edges_sliced(
    const int* __restrict__ src, const int* __restrict__ dst,
    const int* __restrict__ row_start, int* __restrict__ cursor,
    int* __restrict__ csr, int E, int sliceW) {
    const int slice = blockIdx.x & (NSLICE - 1);
    const int chunk = blockIdx.x >> 3;
    const int lo = slice * sliceW, hi = lo + sliceW;
    const int per = (E + NCHUNK - 1) / NCHUNK;
    const int e0 = chunk * per;
    const int e1 = min(e0 + per, E);
    for (int e = e0 + threadIdx.x; e < e1; e += 256) {
        int d = dst[e];
        if (d >= lo && d < hi) {
            int pos = atomicAdd(&cursor[d], 1);
            csr[row_start[d] + pos] = src[e];
        }
    }
}

__global__ __launch_bounds__(256) void scan_partial_kernel(
    const int* __restrict__ deg, int* __restrict__ partials, int n) {
    const int t = threadIdx.x;
    const int i0 = blockIdx.x * 1024 + t * 4;
    int sum = 0;
#pragma unroll
    for (int j = 0; j < 4; j++) { int i = i0 + j; if (i < n) sum += deg[i]; }
#pragma unroll
    for (int off = 32; off; off >>= 1) sum += __shfl_down(sum, off);
    __shared__ int ws[4];
    int lane = t & 63, wid = t >> 6;
    if (lane == 0) ws[wid] = sum;
    __syncthreads();
    if (t == 0) partials[blockIdx.x] = ws[0] + ws[1] + ws[2] + ws[3];
}

__global__ void scan_partials_kernel(int* __restrict__ p, int nb) {
    const int lane = threadIdx.x;  // 64 threads
    int carry = 0;
    for (int base = 0; base < nb; base += 64) {
        int i = base + lane;
        int v = (i < nb) ? p[i] : 0;
        int orig = v;
#pragma unroll
        for (int off = 1; off < 64; off <<= 1) {
            int x = __shfl_up(v, off);
            if (lane >= off) v += x;
        }
        int ex = carry + v - orig;
        if (i < nb) p[i] = ex;
        carry += __shfl(v, 63);
    }
}

__global__ __launch_bounds__(256) void scan_final_kernel(
    const int* __restrict__ deg, const int* __restrict__ pscan,
    int* __restrict__ row_start, int n) {
    const int t = threadIdx.x;
    const int i0 = blockIdx.x * 1024 + t * 4;
    int v0 = (i0 + 0 < n) ? deg[i0 + 0] : 0;
    int v1 = (i0 + 1 < n) ? deg[i0 + 1] : 0;
    int v2 = (i0 + 2 < n) ? deg[i0 + 2] : 0;
    int v3 = (i0 + 3 < n) ? deg[i0 + 3] : 0;
    int tot = v0 + v1 + v2 + v3;
    int lane = t & 63, wid = t >> 6;
    int inc = tot;
#pragma unroll
    for (int off = 1; off < 64; off <<= 1) {
        int x = __shfl_up(inc, off);
        if (lane >= off) inc += x;
    }
    __shared__ int wsum[4];
    if (lane == 63) wsum[wid] = inc;
    __syncthreads();
    int wbase = 0;
    for (int w2 = 0; w2 < wid; w2++) wbase += wsum[w2];
    int r = wbase + inc - tot + pscan[blockIdx.x];
    r += v0; if (i0 + 0 < n) row_start[i0 + 1] = r;
    r += v1; if (i0 + 1 < n) row_start[i0 + 2] = r;
    r += v2; if (i0 + 2 < n) row_start[i0 + 3] = r;
    r += v3; if (i0 + 3 < n) row_start[i0 + 4] = r;
    if (blockIdx.x == 0 && t == 0) row_start[0] = 0;
}

// ---------------- conversions ----------------
__global__ void conv_x_kernel(const float* __restrict__ in, unsigned short* __restrict__ outb,
                              unsigned char* __restrict__ outp, int n4) {
    int i = blockIdx.x * blockDim.x + threadIdx.x;
    if (i >= n4) return;
    float4 v = *reinterpret_cast<const float4*>(in + (size_t)i * 4);
    ushort4 ob = { f2b(v.x), f2b(v.y), f2b(v.z), f2b(v.w) };
    *reinterpret_cast<ushort4*>(outb + (size_t)i * 4) = ob;
    int p0 = __builtin_amdgcn_cvt_pk_fp8_f32(v.x, v.y, 0, false);
    int p1 = __builtin_amdgcn_cvt_pk_fp8_f32(v.z, v.w, 0, false);
    unsigned int packed = (unsigned int)(p0 & 0xffff) | ((unsigned int)p1 << 16);
    *reinterpret_cast<unsigned int*>(outp + (size_t)i * 4) = packed;
}

// all six weight transposes in one dispatch.
__global__ __launch_bounds__(256) void wt_all_kernel(
    const float* __restrict__ Ws0, const float* __restrict__ Wn0,
    const float* __restrict__ Ws1, const float* __restrict__ Wn1,
    const float* __restrict__ Ws2, const float* __restrict__ Wn2,
    unsigned short* __restrict__ Wt0, unsigned short* __restrict__ Wt1,
    unsigned short* __restrict__ Wt2) {
    int b = blockIdx.x;
    const float* W; unsigned short* Wt; int N, koff, Ktot, noff, idx;
    if (b < 1024) {
        int seg = b >> 8; idx = (b & 255) * 256 + threadIdx.x;
        N = 256; Ktot = 512; noff = 0;
        if (seg == 0)      { W = Ws0; Wt = Wt0; koff = 0;   }
        else if (seg == 1) { W = Wn0; Wt = Wt0; koff = 256; }
        else if (seg == 2) { W = Ws1; Wt = Wt1; koff = 0;   }
        else               { W = Wn1; Wt = Wt1; koff = 256; }
    } else {
        int seg = (b - 1024) >> 6; idx = ((b - 1024) & 63) * 256 + threadIdx.x;
        N = 64; Ktot = 256; koff = 0;
        if (seg == 0) { W = Ws2; Wt = Wt2; noff = 0;  }
        else          { W = Wn2; Wt = Wt2; noff = 64; }
    }
    int k = idx / N, n = idx - k * N;
    Wt[(size_t)(n + noff) * Ktot + koff + k] = f2b(W[(size_t)idx]);
}

// ---------------- aggregation ----------------
// fp8 rows (256B). Quarter-wave q covers one edge's row (16 lanes x 16B dwordx4).
__global__ __launch_bounds__(256) void agg256_fp8(
    const unsigned char* __restrict__ hsrc, const int* __restrict__ row_start,
    const int* __restrict__ csr, unsigned short* __restrict__ out, int n) {
    int wv = (blockIdx.x * blockDim.x + threadIdx.x) >> 6;
    int lane = threadIdx.x & 63;
    if (wv >= n) return;
    int s0 = row_start[wv], s1 = row_start[wv + 1];
    int deg = s1 - s0;
    const int q  = lane >> 4;
    const int li = lane & 15;
    float a[16];
#pragma unroll
    for (int k = 0; k < 16; k++) a[k] = 0.f;

    for (int base = s0; base < s1; base += 16) {
        int idx[4];
#pragma unroll
        for (int j = 0; j < 4; j++) {
            int e = base + q + 4 * j;
            idx[j] = csr[e < s1 ? e : s1 - 1];
        }
        uint4 v[4];
#pragma unroll
        for (int j = 0; j < 4; j++) {
            int e = base + q + 4 * j;
            v[j] = make_uint4(0u, 0u, 0u, 0u);
            if (e < s1)
                v[j] = *reinterpret_cast<const uint4*>(hsrc + (size_t)idx[j] * 256 + li * 16);
        }
#pragma unroll
        for (int j = 0; j < 4; j++) acc16p(a, v[j]);
    }
#pragma unroll
    for (int k = 0; k < 16; k++) {
        a[k] += __shfl_xor(a[k], 16);
        a[k] += __shfl_xor(a[k], 32);
    }
    if (q == 0) {
        float sc = 1.0f / (float)max(deg, 1);
        uint4 o0, o1;
        o0.x = ((unsigned)f2b(a[1]  * sc) << 16) | f2b(a[0]  * sc);
        o0.y = ((unsigned)f2b(a[3]  * sc) << 16) | f2b(a[2]  * sc);
        o0.z = ((unsigned)f2b(a[5]  * sc) << 16) | f2b(a[4]  * sc);
        o0.w = ((unsigned)f2b(a[7]  * sc) << 16) | f2b(a[6]  * sc);
        o1.x = ((unsigned)f2b(a[9]  * sc) << 16) | f2b(a[8]  * sc);
        o1.y = ((unsigned)f2b(a[11] * sc) << 16) | f2b(a[10] * sc);
        o1.z = ((unsigned)f2b(a[13] * sc) << 16) | f2b(a[12] * sc);
        o1.w = ((unsigned)f2b(a[15] * sc) << 16) | f2b(a[14] * sc);
        *reinterpret_cast<uint4*>(out + (size_t)wv * 256 + li * 16) = o0;
        *reinterpret_cast<uint4*>(out + (size_t)wv * 256 + li * 16 + 8) = o1;
    }
}

// h2[v][:] = Sself[v][:] + mean_{s in N(v)} Tb[s][:] + b2 ; Tb bf16 64-wide
__global__ __launch_bounds__(256) void agg64_final(
    const unsigned short* __restrict__ t, const int* __restrict__ row_start,
    const int* __restrict__ csr, const float* __restrict__ Sself,
    const float* __restrict__ b2, float* __restrict__ h2, int n) {
    int wv = (blockIdx.x * blockDim.x + threadIdx.x) >> 6;
    int lane = threadIdx.x & 63;
    if (wv >= n) return;
    int s0 = row_start[wv], s1 = row_start[wv + 1];
    int deg = s1 - s0;
    const int g  = lane >> 3;
    const int li = lane & 7;
    float a[8] = {0.f, 0.f, 0.f, 0.f, 0.f, 0.f, 0.f, 0.f};
    for (int base = s0 + g; base < s1; base += 16) {
        int e1 = base + 8;
        int i0 = csr[base];
        int i1 = csr[e1 < s1 ? e1 : s1 - 1];
        uint4 v0 = *reinterpret_cast<const uint4*>(t + (size_t)i0 * 64 + li * 8);
        uint4 v1 = make_uint4(0u, 0u, 0u, 0u);
        if (e1 < s1)
            v1 = *reinterpret_cast<const uint4*>(t + (size_t)i1 * 64 + li * 8);
        acc8(a, v0); acc8(a, v1);
    }
#pragma unroll
    for (int k = 0; k < 8; k++) {
        a[k] += __shfl_xor(a[k], 8);
        a[k] += __shfl_xor(a[k], 16);
        a[k] += __shfl_xor(a[k], 32);
    }
    if (g == 0) {
        float sc = 1.0f / (float)max(deg, 1);
        float4 s0v = *reinterpret_cast<const float4*>(Sself + (size_t)wv * 64 + li * 8);
        float4 s1v = *reinterpret_cast<const float4*>(Sself + (size_t)wv * 64 + li * 8 + 4);
        float4 bb0 = *reinterpret_cast<const float4*>(b2 + li * 8);
        float4 bb1 = *reinterpret_cast<const float4*>(b2 + li * 8 + 4);
        float4 o0 = make_float4(s0v.x + a[0] * sc + bb0.x, s0v.y + a[1] * sc + bb0.y,
                                s0v.z + a[2] * sc + bb0.z, s0v.w + a[3] * sc + bb0.w);
        float4 o1 = make_float4(s1v.x + a[4] * sc + bb1.x, s1v.y + a[5] * sc + bb1.y,
                                s1v.z + a[6] * sc + bb1.z, s1v.w + a[7] * sc + bb1.w);
        *reinterpret_cast<float4*>(h2 + (size_t)wv * 64 + li * 8) = o0;
        *reinterpret_cast<float4*>(h2 + (size_t)wv * 64 + li * 8 + 4) = o1;
    }
}

// ---------------- big GEMM: 128x256 row-stripe, 512 threads ----------------
// C[M,256] = relu( [A|G] @ Wt^T + bias ); A,G bf16 [M][256], Wt bf16 [256][512].
// One block covers all 256 cols -> A|G fetched from HBM exactly once.
// Outputs: outB bf16 [M][256] always; outF fp32 (opt); outP fp8 (opt).
#define BTM 128
#define BTN 256
#define BTK 32

__global__ __launch_bounds__(512, 4) void gemm_big512(
    const unsigned short* __restrict__ A, const unsigned short* __restrict__ G,
    const unsigned short* __restrict__ Wt, const float* __restrict__ bias,
    float* __restrict__ outF, unsigned short* __restrict__ outB,
    unsigned char* __restrict__ outP, int M) {
    __shared__ unsigned short Asb[BTM][BTK];   // 8 KB, lane-linear for lds-dma
    __shared__ unsigned short Bsb[BTN][BTK];   // 16 KB

    const int tid = threadIdx.x;
    const int row0 = blockIdx.x * BTM;
    const int w = tid >> 6, lane = tid & 63;
    const int mw = (w & 1) * 64;       // wave m-offset (2 m-groups)
    const int nw = (w >> 1) * 64;      // wave n-offset (4 n-groups)
    const int lm = lane & 15, lq = lane >> 4;
    const int lr = lane >> 2;          // 0..15
    const int lc = (lane & 3) * 8;     // 0/8/16/24 shorts

    f32x4 acc[4][4];
#pragma unroll
    for (int i = 0; i < 4; i++)
#pragma unroll
        for (int j = 0; j < 4; j++) acc[i][j] = (f32x4)(0.f);

    for (int k0 = 0; k0 < 512; k0 += BTK) {
        const unsigned short* __restrict__ Ap = (k0 >= 256) ? G : A;
        const int kl = k0 & 255;
        // A tile: 128 rows x 64B = 8 KB; wave w stages rows [w*16, w*16+16)
        {
            int gr = row0 + w * 16 + lr;
            if (gr < M)
                gl_lds16(Ap + (size_t)gr * 256 + kl + lc, &Asb[w * 16][0]);
        }
        // B tile: 256 rows x 64B = 16 KB; wave w stages rows [w*32, w*32+32)
#pragma unroll
        for (int h = 0; h < 2; ++h) {
            int gn = w * 32 + h * 16 + lr;
            gl_lds16(Wt + (size_t)gn * 512 + k0 + lc, &Bsb[w * 32 + h * 16][0]);
        }
        __syncthreads();

        frag_ab a[4], b[4];
#pragma unroll
        for (int i = 0; i < 4; i++)
            a[i] = *reinterpret_cast<const frag_ab*>(&Asb[mw + i * 16 + lm][lq * 8]);
#pragma unroll
        for (int j = 0; j < 4; j++)
            b[j] = *reinterpret_cast<const frag_ab*>(&Bsb[nw + j * 16 + lm][lq * 8]);
#pragma unroll
        for (int i = 0; i < 4; i++)
#pragma unroll
            for (int j = 0; j < 4; j++)
                acc[i][j] = __builtin_amdgcn_mfma_f32_16x16x32_bf16(a[i], b[j], acc[i][j], 0, 0, 0);
        __syncthreads();
    }

#pragma unroll
    for (int i = 0; i < 4; i++) {
#pragma unroll
        for (int j = 0; j < 4; j++) {
            int cg = nw + j * 16 + lm;
#pragma unroll
            for (int r = 0; r < 4; r++) {
                int rg = row0 + mw + i * 16 + lq * 4 + r;
                if (rg >= M) continue;
                float v = acc[i][j][r] + bias[cg];
                v = fmaxf(v, 0.f);
                outB[(size_t)rg * 256 + cg] = f2b(v);
                if (outF) outF[(size_t)rg * 256 + cg] = v;
                if (outP) outP[(size_t)rg * 256 + cg] = f2p8(v);
            }
        }
    }
}

// ---------------- layer-2 GEMM (256 thr, TN=64 tiles, split epilogue) ------
#define TM 128
#define TN 64
#define TK 32

__global__ __launch_bounds__(256) void gemm_mfma(
    const unsigned short* __restrict__ A, const unsigned short* __restrict__ Wt,
    float* __restrict__ outF, unsigned short* __restrict__ outB, int M) {
    __shared__ unsigned short Asb[TM][TK];
    __shared__ unsigned short Bsb[TN][TK];

    const int tid = threadIdx.x;
    const int row0 = blockIdx.x * TM;
    const int col0 = blockIdx.y * TN;   // 0 -> Sself (fp32), 64 -> Tb (bf16)

    const int w = tid >> 6, lane = tid & 63;
    const int mw = (w & 1) * 64;
    const int nw = (w >> 1) * 32;
    const int lm = lane & 15, lq = lane >> 4;
    const int lr = lane >> 2;
    const int lc = (lane & 3) * 8;

    f32x4 acc[4][2];
#pragma unroll
    for (int i = 0; i < 4; i++)
#pragma unroll
        for (int j = 0; j < 2; j++) acc[i][j] = (f32x4)(0.f);

    for (int k0 = 0; k0 < 256; k0 += TK) {
#pragma unroll
        for (int h = 0; h < 2; ++h) {
            int r16 = w * 32 + h * 16;
            int gr = row0 + r16 + lr;
            if (gr < M)
                gl_lds16(A + (size_t)gr * 256 + k0 + lc, &Asb[r16][0]);
        }
        {
            int n16 = w * 16;
            int gn = col0 + n16 + lr;
            gl_lds16(Wt + (size_t)gn * 256 + k0 + lc, &Bsb[n16][0]);
        }
        __syncthreads();

        frag_ab a[4], b[2];
#pragma unroll
        for (int i = 0; i < 4; i++)
            a[i] = *reinterpret_cast<const frag_ab*>(&Asb[mw + i * 16 + lm][lq * 8]);
#pragma unroll
        for (int j = 0; j < 2; j++)
            b[j] = *reinterpret_cast<const frag_ab*>(&Bsb[nw + j * 16 + lm][lq * 8]);
#pragma unroll
        for (int i = 0; i < 4; i++)
#pragma unroll
            for (int j = 0; j < 2; j++)
                acc[i][j] = __builtin_amdgcn_mfma_f32_16x16x32_bf16(a[i], b[j], acc[i][j], 0, 0, 0);
        __syncthreads();
    }

#pragma unroll
    for (int i = 0; i < 4; i++) {
#pragma unroll
        for (int j = 0; j < 2; j++) {
            int c = nw + j * 16 + lm;   // 0..63 within tile
#pragma unroll
            for (int r = 0; r < 4; r++) {
                int rg = row0 + mw + i * 16 + lq * 4 + r;
                if (rg >= M) continue;
                float v = acc[i][j][r];
                if (col0 == 0) outF[(size_t)rg * 64 + c] = v;
                else           outB[(size_t)rg * 64 + c] = f2b(v);
            }
        }
    }
}

// ---------------------------------------------------------------------------
extern "C" void kernel_launch(void* const* d_in, const int* in_sizes, int n_in,
                              void* d_out, int out_size, void* d_ws, size_t ws_size,
                              hipStream_t stream) {
    const float* x   = (const float*)d_in[0];
    const int*   src = (const int*)d_in[1];
    const int*   dst = (const int*)d_in[2];
    const float* Ws0 = (const float*)d_in[3];
    const float* Wn0 = (const float*)d_in[4];
    const float* b0  = (const float*)d_in[5];
    const float* Ws1 = (const float*)d_in[6];
    const float* Wn1 = (const float*)d_in[7];
    const float* b1  = (const float*)d_in[8];
    const float* Ws2 = (const float*)d_in[9];
    const float* Wn2 = (const float*)d_in[10];
    const float* b2  = (const float*)d_in[11];

    const int N = in_sizes[0] / 256;   // 50000
    const int E = in_sizes[1];         // 1600000

    float* out = (float*)d_out;
    float* h2 = out;                       // N x 64  (output 0)
    float* h1 = out + (size_t)N * 64;      // N x 256 (output 1, fp32)

    // ---- workspace layout ----
    char* w = (char*)d_ws;
    auto align16 = [](char* p) { return (char*)(((uintptr_t)p + 15) & ~(uintptr_t)15); };
    int* deg       = (int*)w;  w += (size_t)N * 4;
    int* cursor    = (int*)w;  w += (size_t)N * 4;
    int* row_start = (int*)w;  w += (size_t)(N + 1) * 4;
    int* partials  = (int*)w;  w += 256 * 4;
    int* csr       = (int*)w;  w += (size_t)E * 4;
    w = align16(w);
    unsigned short* Wt0   = (unsigned short*)w; w += (size_t)256 * 512 * 2;
    unsigned short* Wt1   = (unsigned short*)w; w += (size_t)256 * 512 * 2;
    unsigned short* Wt2   = (unsigned short*)w; w += (size_t)128 * 256 * 2;  // [Ws2t;Wn2t]
    w = align16(w);
    unsigned short* xb    = (unsigned short*)w; w += (size_t)N * 256 * 2;
    unsigned short* A1b   = (unsigned short*)w; w += (size_t)N * 256 * 2;
    unsigned short* H0b   = (unsigned short*)w; w += (size_t)N * 256 * 2;
    unsigned short* h1b   = (unsigned short*)w; w += (size_t)N * 256 * 2;
    // dead-region aliases (zero extra workspace):
    unsigned char* x8  = (unsigned char*)H0b;  // dead once gemm0 writes H0b
    unsigned char* H08 = (unsigned char*)h1b;  // consumed by agg#2 before gemm1 writes h1b
    unsigned short* Tb    = xb;                // xb dead after gemm0
    float*          Sself = (float*)A1b;       // A1b dead after gemm1

    const int nb = (N + 1023) / 1024;
    const int sliceW = (N + NSLICE - 1) / NSLICE;

    // ---- CSR build (XCD-sliced) ----
    hipMemsetAsync(deg, 0, (size_t)N * 2 * 4, stream);
    count_deg_sliced<<<NSLICE * NCHUNK, 256, 0, stream>>>(dst, deg, E, sliceW);
    scan_partial_kernel<<<nb, 256, 0, stream>>>(deg, partials, N);
    scan_partials_kernel<<<1, 64, 0, stream>>>(partials, nb);
    scan_final_kernel<<<nb, 256, 0, stream>>>(deg, partials, row_start, N);
    scatter_edges_sliced<<<NSLICE * NCHUNK, 256, 0, stream>>>(src, dst, row_start, cursor,
                                                              csr, E, sliceW);

    // ---- conversions ----
    {
        int n4 = N * 256 / 4;
        conv_x_kernel<<<(n4 + 255) / 256, 256, 0, stream>>>(x, xb, x8, n4);
    }
    wt_all_kernel<<<1152, 256, 0, stream>>>(Ws0, Wn0, Ws1, Wn1, Ws2, Wn2, Wt0, Wt1, Wt2);

    dim3 aggGrid((N + 3) / 4);
    dim3 gStripe((N + BTM - 1) / BTM);         // 391 blocks x 512 thr
    dim3 gL2((N + TM - 1) / TM, 2);            // 391 x 2 (Sself | Tb)

    // ---- layer 0 ----
    agg256_fp8<<<aggGrid, 256, 0, stream>>>(x8, row_start, csr, A1b, N);
    gemm_big512<<<gStripe, 512, 0, stream>>>(xb, A1b, Wt0, b0, nullptr, H0b, H08, N);
    // ---- layer 1 ----
    agg256_fp8<<<aggGrid, 256, 0, stream>>>(H08, row_start, csr, A1b, N);
    gemm_big512<<<gStripe, 512, 0, stream>>>(H0b, A1b, Wt1, b1, h1, h1b, nullptr, N);
    // ---- layer 2: stacked gemm + fused aggregate/add ----
    gemm_mfma<<<gL2, 256, 0, stream>>>(h1b, Wt2, Sself, Tb, N);
    agg64_final<<<aggGrid, 256, 0, stream>>>(Tb, row_start, csr, Sself, b2, h2, N);
}